// Round 9
// baseline (130.117 us; speedup 1.0000x reference)
//
#include <hip/hip_runtime.h>
#include <hip/hip_bf16.h>
#include <stdint.h>

// MSDeformableAttention3D, wave-autonomous: bs=1, nq=40000=2500*16, embed=256,
// H=8, L=4, P=4, 16 value rows (14 cells), d=32.
// ONE WAVE (64 lanes) owns 16 queries end-to-end; block = 64 threads; NO
// __syncthreads anywhere (all LDS wave-private; same-wave ordering via lgkmcnt).
// spatial_shapes static: (h,w) = (1,2),(2,2),(2,3),(1,2).
//
// k_prep builds MFMA B-fragment tables in ws (content defined by replicating
// R6's PROVEN staging+read composition):
//   Wfrag[(ks*16+nt)*64+l][j] = bf16(W_so[ks*32+(l>>4)*8+j][nt*16+(l&15)])
//   vfrag[nt2*64+l][j]        = (l>>4)<2 ? bf16(value[(l>>4)*8+j][nt2*16+(l&15)]) : 0
//
// k_fused phases (per wave, serial, no barriers):
//   A/B: off-GEMM 16x256 (two N-halves, acc[8]) -> sOff LDS (swizzled bf16)
//   C:   per-lane (q=l&15, h=(l>>4) and +4): fp32 scores + softmax + bilinear
//        sampling into register bins ws[14]
//   C2:  pack bins -> wsFrag LDS [8 heads][16 q][48B]
//   D:   per-head MFMA (wsum 16x16pad32 @ value 32x32) -> out fp32

typedef __attribute__((ext_vector_type(8))) short short8;
typedef __attribute__((ext_vector_type(4))) float float4_;

#define SOFF_B 0         // sOff: 16 rows x 512B, XOR-swizzled
#define WSF_B 8192       // wsFrag: 8 heads x 16 rows x 48B = 6144
#define SMEM_BYTES 14336

static __device__ __forceinline__ uint16_t f2bf(float f) {
    union { float f; uint32_t u; } a; a.f = f;
    uint32_t r = a.u + 0x7fffu + ((a.u >> 16) & 1u);   // RNE
    return (uint16_t)(r >> 16);
}
static __device__ __forceinline__ float bf2f(uint16_t b) {
    union { uint32_t u; float f; } a; a.u = ((uint32_t)b) << 16;
    return a.f;
}

// outer-product scatter into compile-time bins; OOB corners match no cell.
template <int H_, int W_, int ST_>
static __device__ __forceinline__ void scatter(float* ws, float a, float x, float y) {
    float x0f = floorf(x), y0f = floorf(y);
    float fx = x - x0f, fy = y - y0f;
    int ix0 = (int)x0f, iy0 = (int)y0f;
    float xc[W_], yc[H_];
#pragma unroll
    for (int cx = 0; cx < W_; ++cx)
        xc[cx] = (ix0 == cx) ? (1.f - fx) : ((ix0 + 1 == cx) ? fx : 0.f);
#pragma unroll
    for (int cy = 0; cy < H_; ++cy)
        yc[cy] = ((iy0 == cy) ? (1.f - fy) : ((iy0 + 1 == cy) ? fy : 0.f)) * a;
#pragma unroll
    for (int cy = 0; cy < H_; ++cy)
#pragma unroll
        for (int cx = 0; cx < W_; ++cx)
            ws[ST_ + cy * W_ + cx] += xc[cx] * yc[cy];
}

// ---------------- k_prep: fragment tables ----------------
__global__ __launch_bounds__(256) void k_prep(const float* __restrict__ W,
                                              const float* __restrict__ value,
                                              uint16_t* __restrict__ tab) {
    int tid = threadIdx.x, b = blockIdx.x;
    if (b < 32) {                       // Wfrag: 8192 fragments
        int f = b * 256 + tid;
        int l = f & 63, nt = (f >> 6) & 15, ks = (f >> 10) & 7;
        int col = nt * 16 + (l & 15);
        int kb = ks * 32 + (l >> 4) * 8;
        uint16_t* dst = tab + (size_t)f * 8;
#pragma unroll
        for (int j = 0; j < 8; ++j) dst[j] = f2bf(W[(size_t)(kb + j) * 256 + col]);
    } else {                            // vfrag: 1024 fragments
        int f = (b - 32) * 256 + tid;   // 0..1023
        int l = f & 63, nt2 = f >> 6;
        int col = nt2 * 16 + (l & 15);
        int g = l >> 4;
        uint16_t* dst = tab + 65536 + (size_t)f * 8;
#pragma unroll
        for (int j = 0; j < 8; ++j)
            dst[j] = (g < 2) ? f2bf(value[(size_t)(g * 8 + j) * 256 + col]) : (uint16_t)0;
    }
}

// ---------------- fused wave-autonomous kernel ----------------
__global__ __launch_bounds__(64) void k_fused(const float* __restrict__ q,
                                              const float* __restrict__ key,
                                              const float* __restrict__ refp,
                                              const uint16_t* __restrict__ Wfrag,
                                              const uint16_t* __restrict__ vfrag,
                                              const float* __restrict__ bso,
                                              float* __restrict__ out) {
    __shared__ __align__(16) char smem[SMEM_BYTES];
    int l = threadIdx.x;
    int g = l >> 4, lr = l & 15;
    int qb = blockIdx.x * 16;
    int qa = qb + lr;

    // ---- phase A+B: offsets GEMM (two N-halves of 128), epilogue -> sOff ----
    for (int np = 0; np < 2; ++np) {
        float4_ acc[8];
#pragma unroll
        for (int i = 0; i < 8; ++i) acc[i] = (float4_)0.f;
#pragma unroll
        for (int ks = 0; ks < 8; ++ks) {
            const float4_* ap = (const float4_*)(q + (size_t)(qb + lr) * 256 + ks * 32 + g * 8);
            float4_ a0 = ap[0], a1 = ap[1];
            union { uint32_t u[4]; short8 v; } af;
            af.u[0] = (uint32_t)f2bf(a0.x) | ((uint32_t)f2bf(a0.y) << 16);
            af.u[1] = (uint32_t)f2bf(a0.z) | ((uint32_t)f2bf(a0.w) << 16);
            af.u[2] = (uint32_t)f2bf(a1.x) | ((uint32_t)f2bf(a1.y) << 16);
            af.u[3] = (uint32_t)f2bf(a1.z) | ((uint32_t)f2bf(a1.w) << 16);
#pragma unroll
            for (int nt = 0; nt < 8; ++nt) {
                short8 bf = *(const short8*)(Wfrag
                    + ((size_t)(ks * 16 + np * 8 + nt) * 64 + l) * 8);
                acc[nt] = __builtin_amdgcn_mfma_f32_16x16x32_bf16(af.v, bf, acc[nt], 0, 0, 0);
            }
        }
#pragma unroll
        for (int nt = 0; nt < 8; ++nt) {
            int col = (np * 8 + nt) * 16 + lr;
            float b = bso[col];
#pragma unroll
            for (int r = 0; r < 4; ++r) {
                int row = g * 4 + r;
                *(uint16_t*)(smem + SOFF_B + row * 512 + ((col * 2) ^ ((row & 7) << 4))) =
                    f2bf(acc[nt][r] + b);
            }
        }
    }

    // ---- phase C: per-lane (q=lr, h=g / g+4): scores+softmax+sampling ----
    float4_ r01 = *(const float4_*)(refp + (size_t)qa * 8);
    float4_ r23 = *(const float4_*)(refp + (size_t)qa * 8 + 4);
    float rx[4] = {r01.x, r01.z, r23.x, r23.z};
    float ry[4] = {r01.y, r01.w, r23.y, r23.w};

    float wsA[14], wsB[14];

    // norm by (W,H)[pp]: W={2,2,3,2}, H={1,2,2,1}; sample grid by lev.
#define SAMPLE_PT(WS, J, PP, GH, GW, ST, NW, NH)                              \
    {                                                                         \
        float ox = bf2f((uint16_t)ovl.s[2 * (J)]);                            \
        float oy = bf2f((uint16_t)ovl.s[2 * (J) + 1]);                        \
        float x = (rx[PP] + ox * (NW)) * (float)(GW)-0.5f;                    \
        float y = (ry[PP] + oy * (NH)) * (float)(GH)-0.5f;                    \
        scatter<GH, GW, ST>(WS, sc[4 * LEV + (J)], x, y);                     \
    }
#define DO_PASS(WS, HH)                                                           \
    {                                                                             \
        const int h = (HH);                                                       \
        float sc[16];                                                             \
        {                                                                         \
            const float4_* qp = (const float4_*)(q + (size_t)qa * 256 + h * 32);  \
            float4_ qv[8];                                                        \
            _Pragma("unroll") for (int j = 0; j < 8; ++j) qv[j] = qp[j];          \
            _Pragma("unroll") for (int kk = 0; kk < 16; ++kk) {                   \
                const float4_* kp = (const float4_*)(key + kk * 256 + h * 32);    \
                float a = 0.f;                                                    \
                _Pragma("unroll") for (int j = 0; j < 8; ++j) {                   \
                    float4_ kv = kp[j];                                           \
                    a += qv[j].x * kv.x + qv[j].y * kv.y + qv[j].z * kv.z         \
                       + qv[j].w * kv.w;                                          \
                }                                                                 \
                sc[kk] = a;                                                       \
            }                                                                     \
            float m = sc[0];                                                      \
            _Pragma("unroll") for (int kk = 1; kk < 16; ++kk) m = fmaxf(m, sc[kk]); \
            float s = 0.f;                                                        \
            _Pragma("unroll") for (int kk = 0; kk < 16; ++kk) {                   \
                sc[kk] = __expf(sc[kk] - m); s += sc[kk];                         \
            }                                                                     \
            float inv = 1.f / s;                                                  \
            _Pragma("unroll") for (int kk = 0; kk < 16; ++kk) sc[kk] *= inv;      \
        }                                                                         \
        _Pragma("unroll") for (int j = 0; j < 14; ++j) WS[j] = 0.f;               \
        union OvU { short8 v; short s[8]; } ovl;                                  \
        {                                                                         \
            enum { LEV = 0 };                                                     \
            ovl.v = *(const short8*)(smem + SOFF_B + lr * 512                     \
                        + ((h * 64 + LEV * 16) ^ ((lr & 7) << 4)));               \
            SAMPLE_PT(WS, 0, 0, 1, 2, 0, 0.5f, 1.0f)                              \
            SAMPLE_PT(WS, 1, 1, 1, 2, 0, 0.5f, 0.5f)                              \
            SAMPLE_PT(WS, 2, 2, 1, 2, 0, (1.f / 3.f), 0.5f)                       \
            SAMPLE_PT(WS, 3, 3, 1, 2, 0, 0.5f, 1.0f)                              \
        }                                                                         \
        {                                                                         \
            enum { LEV = 1 };                                                     \
            ovl.v = *(const short8*)(smem + SOFF_B + lr * 512                     \
                        + ((h * 64 + LEV * 16) ^ ((lr & 7) << 4)));               \
            SAMPLE_PT(WS, 0, 0, 2, 2, 2, 0.5f, 1.0f)                              \
            SAMPLE_PT(WS, 1, 1, 2, 2, 2, 0.5f, 0.5f)                              \
            SAMPLE_PT(WS, 2, 2, 2, 2, 2, (1.f / 3.f), 0.5f)                       \
            SAMPLE_PT(WS, 3, 3, 2, 2, 2, 0.5f, 1.0f)                              \
        }                                                                         \
        {                                                                         \
            enum { LEV = 2 };                                                     \
            ovl.v = *(const short8*)(smem + SOFF_B + lr * 512                     \
                        + ((h * 64 + LEV * 16) ^ ((lr & 7) << 4)));               \
            SAMPLE_PT(WS, 0, 0, 2, 3, 6, 0.5f, 1.0f)                              \
            SAMPLE_PT(WS, 1, 1, 2, 3, 6, 0.5f, 0.5f)                              \
            SAMPLE_PT(WS, 2, 2, 2, 3, 6, (1.f / 3.f), 0.5f)                       \
            SAMPLE_PT(WS, 3, 3, 2, 3, 6, 0.5f, 1.0f)                              \
        }                                                                         \
        {                                                                         \
            enum { LEV = 3 };                                                     \
            ovl.v = *(const short8*)(smem + SOFF_B + lr * 512                     \
                        + ((h * 64 + LEV * 16) ^ ((lr & 7) << 4)));               \
            SAMPLE_PT(WS, 0, 0, 1, 2, 12, 0.5f, 1.0f)                             \
            SAMPLE_PT(WS, 1, 1, 1, 2, 12, 0.5f, 0.5f)                             \
            SAMPLE_PT(WS, 2, 2, 1, 2, 12, (1.f / 3.f), 0.5f)                      \
            SAMPLE_PT(WS, 3, 3, 1, 2, 12, 0.5f, 1.0f)                             \
        }                                                                         \
    }

    DO_PASS(wsA, g)
    DO_PASS(wsB, g + 4)
#undef DO_PASS
#undef SAMPLE_PT

    // ---- phase C2: pack bins -> wsFrag [head][q row lr][48B] ----
    {
        union PkU { uint32_t u[8]; short8 v2[2]; } pk;
#pragma unroll
        for (int j = 0; j < 7; ++j)
            pk.u[j] = (uint32_t)f2bf(wsA[2 * j]) | ((uint32_t)f2bf(wsA[2 * j + 1]) << 16);
        pk.u[7] = 0;
        *(short8*)(smem + WSF_B + g * 768 + lr * 48)      = pk.v2[0];
        *(short8*)(smem + WSF_B + g * 768 + lr * 48 + 16) = pk.v2[1];
#pragma unroll
        for (int j = 0; j < 7; ++j)
            pk.u[j] = (uint32_t)f2bf(wsB[2 * j]) | ((uint32_t)f2bf(wsB[2 * j + 1]) << 16);
        pk.u[7] = 0;
        *(short8*)(smem + WSF_B + (g + 4) * 768 + lr * 48)      = pk.v2[0];
        *(short8*)(smem + WSF_B + (g + 4) * 768 + lr * 48 + 16) = pk.v2[1];
    }

    // ---- phase D: per-head out = wsum @ value ----
    {
        union ZU { uint32_t u[4]; short8 v; } az;
        az.u[0] = 0; az.u[1] = 0; az.u[2] = 0; az.u[3] = 0;
        float4_ z4 = (float4_)0.f;
#pragma unroll
        for (int hp = 0; hp < 8; ++hp) {
            short8 af2 = (g < 2)
                ? *(const short8*)(smem + WSF_B + hp * 768 + lr * 48 + g * 16)
                : az.v;
#pragma unroll
            for (int nt2 = 0; nt2 < 2; ++nt2) {
                short8 vb = *(const short8*)(vfrag + ((size_t)(hp * 2 + nt2) * 64 + l) * 8);
                float4_ o = __builtin_amdgcn_mfma_f32_16x16x32_bf16(af2, vb, z4, 0, 0, 0);
#pragma unroll
                for (int r = 0; r < 4; ++r)
                    out[(size_t)(qb + g * 4 + r) * 256 + hp * 32 + nt2 * 16 + lr] = o[r];
            }
        }
    }
}

extern "C" void kernel_launch(void* const* d_in, const int* in_sizes, int n_in,
                              void* d_out, int out_size, void* d_ws, size_t ws_size,
                              hipStream_t stream) {
    (void)in_sizes; (void)n_in; (void)out_size; (void)ws_size;
    const float* query = (const float*)d_in[0];
    const float* key   = (const float*)d_in[1];
    const float* value = (const float*)d_in[2];
    const float* refp  = (const float*)d_in[3];
    const float* Wso   = (const float*)d_in[5];
    const float* bso   = (const float*)d_in[6];
    uint16_t* tab = (uint16_t*)d_ws;

    hipLaunchKernelGGL(k_prep, dim3(36), dim3(256), 0, stream, Wso, value, tab);
    hipLaunchKernelGGL(k_fused, dim3(2500), dim3(64), 0, stream,
                       query, key, refp, tab, tab + 65536, bso, (float*)d_out);
}

// Round 10
// 80.736 us; speedup vs baseline: 1.6116x; 1.6116x over previous
//
#include <hip/hip_runtime.h>
#include <hip/hip_bf16.h>
#include <stdint.h>

// MSDeformableAttention3D, two-kernel split: bs=1, nq=40000=1250*32, embed=256,
// H=8, L=4, P=4, 16 value rows (14 cells), d=32.
// spatial_shapes static: (h,w) = (1,2),(2,2),(2,3),(1,2).
//
// R2-R9 lesson: monolithic phase-serial blocks are exposed-latency-bound
// (VALUBusy <=23%, ~21 barriers each draining vmcnt). Split:
//  k_prep: W_so -> MFMA B-fragment table (R9-proven mapping).
//  k1 (ZERO barriers, ZERO LDS): off-GEMM w/ table B-frags + per-lane global
//     A-frags -> off_g bf16; f32 scores+softmax (R8-proven) -> wg_g f32.
//  k2 (ONE barrier): sampling from off_g/wg_g (R8-verbatim math) -> register
//     bins -> wsFrag LDS -> per-head MFMA w/ global value (R8-verbatim) -> out.
//
// ws layout: [0,128K) Wfrag; [128K, +20.48M) off_g bf16 [40000][256];
//            then wg_g f32 [40000][128].

typedef __attribute__((ext_vector_type(8))) short short8;
typedef __attribute__((ext_vector_type(4))) float float4_;

#define OFF_G_OFF 131072
#define WG_G_OFF  (131072 + 40000 * 512)

static __device__ __forceinline__ uint16_t f2bf(float f) {
    union { float f; uint32_t u; } a; a.f = f;
    uint32_t r = a.u + 0x7fffu + ((a.u >> 16) & 1u);   // RNE
    return (uint16_t)(r >> 16);
}
static __device__ __forceinline__ float bf2f(uint16_t b) {
    union { uint32_t u; float f; } a; a.u = ((uint32_t)b) << 16;
    return a.f;
}

// outer-product scatter into compile-time bins; OOB corners match no cell.
template <int H_, int W_, int ST_>
static __device__ __forceinline__ void scatter(float* ws, float a, float x, float y) {
    float x0f = floorf(x), y0f = floorf(y);
    float fx = x - x0f, fy = y - y0f;
    int ix0 = (int)x0f, iy0 = (int)y0f;
    float xc[W_], yc[H_];
#pragma unroll
    for (int cx = 0; cx < W_; ++cx)
        xc[cx] = (ix0 == cx) ? (1.f - fx) : ((ix0 + 1 == cx) ? fx : 0.f);
#pragma unroll
    for (int cy = 0; cy < H_; ++cy)
        yc[cy] = ((iy0 == cy) ? (1.f - fy) : ((iy0 + 1 == cy) ? fy : 0.f)) * a;
#pragma unroll
    for (int cy = 0; cy < H_; ++cy)
#pragma unroll
        for (int cx = 0; cx < W_; ++cx)
            ws[ST_ + cy * W_ + cx] += xc[cx] * yc[cy];
}

// ---------------- k_prep: Wfrag table (R9-proven mapping) ----------------
// Wfrag[(ks*16+nt)*64+l][j] = bf16(W_so[ks*32+(l>>4)*8+j][nt*16+(l&15)])
__global__ __launch_bounds__(256) void k_prep(const float* __restrict__ W,
                                              uint16_t* __restrict__ tab) {
    int f = blockIdx.x * 256 + threadIdx.x;
    int l = f & 63, nt = (f >> 6) & 15, ks = (f >> 10) & 7;
    int col = nt * 16 + (l & 15);
    int kb = ks * 32 + (l >> 4) * 8;
    uint16_t* dst = tab + (size_t)f * 8;
#pragma unroll
    for (int j = 0; j < 8; ++j) dst[j] = f2bf(W[(size_t)(kb + j) * 256 + col]);
}

// ---------------- k1: off-GEMM + scores (zero barriers, zero LDS) ----------------
__global__ __launch_bounds__(256) void k1(const float* __restrict__ q,
                                          const float* __restrict__ key,
                                          const uint16_t* __restrict__ Wfrag,
                                          const float* __restrict__ bso,
                                          uint16_t* __restrict__ off_g,
                                          float* __restrict__ wg_g) {
    int t = threadIdx.x;
    int w = t >> 6, l = t & 63;
    int g = l >> 4, lrow = l & 15;
    int qbase = blockIdx.x * 32;
    int h2 = t >> 5, ql = t & 31;
    int qa = qbase + ql;

    // ---- off-GEMM 32x256: A per-lane from global, B from Wfrag table ----
    float4_ acc[2][4];
#pragma unroll
    for (int i = 0; i < 2; ++i)
#pragma unroll
        for (int j = 0; j < 4; ++j) acc[i][j] = (float4_)0.f;

#pragma unroll
    for (int ks = 0; ks < 8; ++ks) {
        short8 af[2], bf[4];
#pragma unroll
        for (int mi = 0; mi < 2; ++mi) {
            const float4_* ap = (const float4_*)(q
                + (size_t)(qbase + mi * 16 + lrow) * 256 + ks * 32 + g * 8);
            float4_ a0 = ap[0], a1 = ap[1];
            union { uint32_t u[4]; short8 v; } pk;
            pk.u[0] = (uint32_t)f2bf(a0.x) | ((uint32_t)f2bf(a0.y) << 16);
            pk.u[1] = (uint32_t)f2bf(a0.z) | ((uint32_t)f2bf(a0.w) << 16);
            pk.u[2] = (uint32_t)f2bf(a1.x) | ((uint32_t)f2bf(a1.y) << 16);
            pk.u[3] = (uint32_t)f2bf(a1.z) | ((uint32_t)f2bf(a1.w) << 16);
            af[mi] = pk.v;
        }
#pragma unroll
        for (int ni = 0; ni < 4; ++ni)
            bf[ni] = *(const short8*)(Wfrag
                + ((size_t)(ks * 16 + w * 4 + ni) * 64 + l) * 8);
#pragma unroll
        for (int mi = 0; mi < 2; ++mi)
#pragma unroll
            for (int ni = 0; ni < 4; ++ni)
                acc[mi][ni] = __builtin_amdgcn_mfma_f32_16x16x32_bf16(
                    af[mi], bf[ni], acc[mi][ni], 0, 0, 0);
    }

    // ---- epilogue: +bias -> off_g bf16 [q][256] ----
#pragma unroll
    for (int mi = 0; mi < 2; ++mi)
#pragma unroll
        for (int ni = 0; ni < 4; ++ni) {
            int col = w * 64 + ni * 16 + lrow;
            float b = bso[col];
#pragma unroll
            for (int r = 0; r < 4; ++r)
                off_g[(size_t)(qbase + mi * 16 + g * 4 + r) * 256 + col] =
                    f2bf(acc[mi][ni][r] + b);
        }

    // ---- scores (thread = (h2, ql)) f32 + softmax -> wg_g [q][128] ----
    float sc[16];
#pragma unroll
    for (int kk = 0; kk < 16; ++kk) sc[kk] = 0.f;
#pragma unroll
    for (int half = 0; half < 2; ++half) {
        const float4_* qp = (const float4_*)(q + (size_t)qa * 256 + h2 * 32 + half * 16);
        float4_ qv[4];
#pragma unroll
        for (int j = 0; j < 4; ++j) qv[j] = qp[j];
#pragma unroll
        for (int kk = 0; kk < 16; ++kk) {
            const float4_* kp = (const float4_*)(key + kk * 256 + h2 * 32 + half * 16);
            float a = 0.f;
#pragma unroll
            for (int j = 0; j < 4; ++j) {
                float4_ kv = kp[j];
                a += qv[j].x * kv.x + qv[j].y * kv.y + qv[j].z * kv.z + qv[j].w * kv.w;
            }
            sc[kk] += a;
        }
    }
    {
        float m = sc[0];
#pragma unroll
        for (int kk = 1; kk < 16; ++kk) m = fmaxf(m, sc[kk]);
        float s = 0.f;
#pragma unroll
        for (int kk = 0; kk < 16; ++kk) { sc[kk] = __expf(sc[kk] - m); s += sc[kk]; }
        float inv = 1.f / s;
#pragma unroll
        for (int kk = 0; kk < 16; ++kk) sc[kk] *= inv;
    }
#pragma unroll
    for (int kk = 0; kk < 16; ++kk)
        wg_g[(size_t)qa * 128 + h2 * 16 + kk] = sc[kk];
}

// ---------------- k2: sampling + output (one barrier) ----------------
__global__ __launch_bounds__(256) void k2(const float* __restrict__ refp,
                                          const uint16_t* __restrict__ off_g,
                                          const float* __restrict__ wg_g,
                                          const float* __restrict__ value,
                                          float* __restrict__ out) {
    __shared__ __align__(16) char smem[12288];   // wsFrag [256][48B]
    int t = threadIdx.x;
    int w = t >> 6, l = t & 63;
    int g = l >> 4, lrow = l & 15;
    int qbase = blockIdx.x * 32;
    int h2 = t >> 5, ql = t & 31;
    int qa = qbase + ql;

    // ---- load softmaxed weights ----
    float sc[16];
    {
        const float4_* sp = (const float4_*)(wg_g + (size_t)qa * 128 + h2 * 16);
#pragma unroll
        for (int j = 0; j < 4; ++j) {
            float4_ v = sp[j];
            sc[4 * j] = v.x; sc[4 * j + 1] = v.y; sc[4 * j + 2] = v.z; sc[4 * j + 3] = v.w;
        }
    }

    // ---- sampling into register bins (R8-verbatim math; offsets from global) ----
    float4_ r01 = *(const float4_*)(refp + (size_t)qa * 8);
    float4_ r23 = *(const float4_*)(refp + (size_t)qa * 8 + 4);
    float rx[4] = {r01.x, r01.z, r23.x, r23.z};
    float ry[4] = {r01.y, r01.w, r23.y, r23.w};

    float ws[14];
#pragma unroll
    for (int j = 0; j < 14; ++j) ws[j] = 0.f;

    // norm by (W,H)[pp]: W={2,2,3,2}, H={1,2,2,1}; sample grid by lev.
#define SAMPLE_PT(J, PP, GH, GW, ST, NW, NH)                                  \
    {                                                                         \
        float ox = bf2f((uint16_t)ovl.s[2 * (J)]);                            \
        float oy = bf2f((uint16_t)ovl.s[2 * (J) + 1]);                        \
        float x = (rx[PP] + ox * (NW)) * (float)(GW)-0.5f;                    \
        float y = (ry[PP] + oy * (NH)) * (float)(GH)-0.5f;                    \
        scatter<GH, GW, ST>(ws, sc[4 * LEV + (J)], x, y);                     \
    }
    {
        union OvU { short8 v; short s[8]; } ovl;
        const short8* ob = (const short8*)(off_g + (size_t)qa * 256 + h2 * 32);
#define LEV 0
        ovl.v = ob[LEV];
        SAMPLE_PT(0, 0, 1, 2, 0, 0.5f, 1.0f)
        SAMPLE_PT(1, 1, 1, 2, 0, 0.5f, 0.5f)
        SAMPLE_PT(2, 2, 1, 2, 0, (1.f / 3.f), 0.5f)
        SAMPLE_PT(3, 3, 1, 2, 0, 0.5f, 1.0f)
#undef LEV
#define LEV 1
        ovl.v = ob[LEV];
        SAMPLE_PT(0, 0, 2, 2, 2, 0.5f, 1.0f)
        SAMPLE_PT(1, 1, 2, 2, 2, 0.5f, 0.5f)
        SAMPLE_PT(2, 2, 2, 2, 2, (1.f / 3.f), 0.5f)
        SAMPLE_PT(3, 3, 2, 2, 2, 0.5f, 1.0f)
#undef LEV
#define LEV 2
        ovl.v = ob[LEV];
        SAMPLE_PT(0, 0, 2, 3, 6, 0.5f, 1.0f)
        SAMPLE_PT(1, 1, 2, 3, 6, 0.5f, 0.5f)
        SAMPLE_PT(2, 2, 2, 3, 6, (1.f / 3.f), 0.5f)
        SAMPLE_PT(3, 3, 2, 3, 6, 0.5f, 1.0f)
#undef LEV
#define LEV 3
        ovl.v = ob[LEV];
        SAMPLE_PT(0, 0, 1, 2, 12, 0.5f, 1.0f)
        SAMPLE_PT(1, 1, 1, 2, 12, 0.5f, 0.5f)
        SAMPLE_PT(2, 2, 1, 2, 12, (1.f / 3.f), 0.5f)
        SAMPLE_PT(3, 3, 1, 2, 12, 0.5f, 1.0f)
#undef LEV
    }
#undef SAMPLE_PT

    // ---- pack ws -> wsFrag [256][48B] (row = t = h2*32+ql) ----
    {
        union PkU { uint32_t u[8]; short8 v2[2]; } pk;
#pragma unroll
        for (int j = 0; j < 7; ++j)
            pk.u[j] = (uint32_t)f2bf(ws[2 * j]) | ((uint32_t)f2bf(ws[2 * j + 1]) << 16);
        pk.u[7] = 0;
        *(short8*)(smem + t * 48)      = pk.v2[0];
        *(short8*)(smem + t * 48 + 16) = pk.v2[1];
    }
    __syncthreads();

    // ---- out = wsum @ value; wave w serves heads {2w, 2w+1} (R8-verbatim) ----
    {
        union ZU { uint32_t u[4]; short8 v; } az;
        az.u[0] = 0; az.u[1] = 0; az.u[2] = 0; az.u[3] = 0;
#pragma unroll
        for (int hh = 0; hh < 2; ++hh) {
            int h = 2 * w + hh;
            union VbU { short8 v; uint16_t u[8]; } vb[2];
#pragma unroll
            for (int nt = 0; nt < 2; ++nt) {
                if (g < 2) {
                    int col = h * 32 + nt * 16 + lrow;
#pragma unroll
                    for (int j = 0; j < 8; ++j)
                        vb[nt].u[j] = f2bf(value[(g * 8 + j) * 256 + col]);
                } else {
                    vb[nt].v = az.v;
                }
            }
            float4_ acc2[2][2];
#pragma unroll
            for (int i = 0; i < 2; ++i)
#pragma unroll
                for (int j = 0; j < 2; ++j) acc2[i][j] = (float4_)0.f;
#pragma unroll
            for (int mt = 0; mt < 2; ++mt) {
                short8 af = (g < 2)
                    ? *(const short8*)(smem + (h * 32 + mt * 16 + lrow) * 48 + g * 16)
                    : az.v;
#pragma unroll
                for (int nt = 0; nt < 2; ++nt)
                    acc2[mt][nt] = __builtin_amdgcn_mfma_f32_16x16x32_bf16(
                        af, vb[nt].v, acc2[mt][nt], 0, 0, 0);
            }
#pragma unroll
            for (int mt = 0; mt < 2; ++mt)
#pragma unroll
                for (int nt = 0; nt < 2; ++nt)
#pragma unroll
                    for (int r = 0; r < 4; ++r)
                        out[(size_t)(qbase + mt * 16 + g * 4 + r) * 256
                            + h * 32 + nt * 16 + lrow] = acc2[mt][nt][r];
        }
    }
}

extern "C" void kernel_launch(void* const* d_in, const int* in_sizes, int n_in,
                              void* d_out, int out_size, void* d_ws, size_t ws_size,
                              hipStream_t stream) {
    (void)in_sizes; (void)n_in; (void)out_size; (void)ws_size;
    const float* query = (const float*)d_in[0];
    const float* key   = (const float*)d_in[1];
    const float* value = (const float*)d_in[2];
    const float* refp  = (const float*)d_in[3];
    const float* Wso   = (const float*)d_in[5];
    const float* bso   = (const float*)d_in[6];
    char* ws = (char*)d_ws;
    uint16_t* Wfrag = (uint16_t*)ws;
    uint16_t* off_g = (uint16_t*)(ws + OFF_G_OFF);
    float*    wg_g  = (float*)(ws + WG_G_OFF);

    hipLaunchKernelGGL(k_prep, dim3(32), dim3(256), 0, stream, Wso, Wfrag);
    hipLaunchKernelGGL(k1, dim3(1250), dim3(256), 0, stream,
                       query, key, Wfrag, bso, off_g, wg_g);
    hipLaunchKernelGGL(k2, dim3(1250), dim3(256), 0, stream,
                       refp, off_g, wg_g, value, (float*)d_out);
}